// Round 1
// baseline (2737.618 us; speedup 1.0000x reference)
//
#include <hip/hip_runtime.h>

#define LOG2F 0.69314718055994530942f

// ---------------------------------------------------------------------------
// Kernel 0: detect whether edge_index is int64 or int32 in memory.
// If int64 (values < 2^31), every odd 32-bit word is 0. If int32, odd words
// are random node indices (P(zero) ~ 4e-5 each; 200 samples -> certain).
// ---------------------------------------------------------------------------
__global__ void detect_idx_kernel(const unsigned int* __restrict__ words,
                                  int* __restrict__ flag) {
    if (threadIdx.x == 0 && blockIdx.x == 0) {
        int is64 = 1;
        for (int w = 1; w < 400; w += 2) {
            if (words[w] != 0u) { is64 = 0; break; }
        }
        *flag = is64;
    }
}

// ---------------------------------------------------------------------------
// Kernel 1: scatter-add edge_feats into agg[node][K*F].
// One thread per float4 of each edge's 512-float row. Coalesced loads,
// 4 f32 atomicAdds (targets live in L2/LLC: agg = 51.2 MB).
// ---------------------------------------------------------------------------
__global__ __launch_bounds__(256) void scatter_kernel(
        const float4* __restrict__ edge_feats4,
        const void* __restrict__ idx,
        const int* __restrict__ flag,
        float* __restrict__ agg,
        int E) {
    long long gid = (long long)blockIdx.x * blockDim.x + threadIdx.x;
    long long total = (long long)E * 128;   // K*F/4 = 128 float4 per edge
    if (gid >= total) return;
    int e = (int)(gid >> 7);
    int q = (int)(gid & 127);
    int n;
    if (*flag) {
        n = (int)((const long long*)idx)[E + e];   // edge_index[1][e], int64
    } else {
        n = ((const int*)idx)[E + e];              // int32 layout
    }
    float4 v = edge_feats4[(long long)e * 128 + q];
    float* dst = agg + (long long)n * 512 + q * 4;
    atomicAdd(dst + 0, v.x);
    atomicAdd(dst + 1, v.y);
    atomicAdd(dst + 2, v.z);
    atomicAdd(dst + 3, v.w);
}

// ---------------------------------------------------------------------------
// Kernel 2: per-node fused MLP + elementwise adds.
// Block = 256 threads, 16 nodes/block.
// Phase 1: s = sum_k agg[n,k,:] -> LDS; out1 = node_vec + agg[:,1:,:]
// Phase 2: h1 = ssp(s @ W1 + b1) -> LDS
// Phase 3: out0 = node_sca + h1 @ W2 + b2
// Thread j in [0,128) owns output column j; tid>=128 half handles nodes 8..15.
// Each W element loaded once per half-block, reused for 8 nodes (registers).
// ---------------------------------------------------------------------------
__global__ __launch_bounds__(256) void node_kernel(
        const float* __restrict__ agg,
        const float* __restrict__ node_sca,
        const float* __restrict__ node_vec,
        const float* __restrict__ W1, const float* __restrict__ b1,
        const float* __restrict__ W2, const float* __restrict__ b2,
        float* __restrict__ out0, float* __restrict__ out1,
        int N) {
    __shared__ float s_lds[16][128];
    __shared__ float h_lds[16][128];

    const int tid = threadIdx.x;
    const int nbase = blockIdx.x * 16;

    // ---- Phase 1: reduce agg over K, write out1 ----
    {
        const int q = tid & 31;     // float4 index within a 128-float row
        const int mloc = tid >> 5;  // 0..7
        #pragma unroll
        for (int step = 0; step < 2; ++step) {
            const int m = mloc + step * 8;
            const int n = nbase + m;
            if (n < N) {
                const float4* aggrow = (const float4*)(agg + (long long)n * 512);
                float4 a0 = aggrow[q];
                float4 a1 = aggrow[32 + q];
                float4 a2 = aggrow[64 + q];
                float4 a3 = aggrow[96 + q];
                float4 s4;
                s4.x = a0.x + a1.x + a2.x + a3.x;
                s4.y = a0.y + a1.y + a2.y + a3.y;
                s4.z = a0.z + a1.z + a2.z + a3.z;
                s4.w = a0.w + a1.w + a2.w + a3.w;
                *(float4*)&s_lds[m][q * 4] = s4;

                const float4* nv4 = (const float4*)(node_vec + (long long)n * 384);
                float4* o1 = (float4*)(out1 + (long long)n * 384);
                float4 v;
                v = nv4[q];
                o1[q]      = make_float4(v.x + a1.x, v.y + a1.y, v.z + a1.z, v.w + a1.w);
                v = nv4[32 + q];
                o1[32 + q] = make_float4(v.x + a2.x, v.y + a2.y, v.z + a2.z, v.w + a2.w);
                v = nv4[64 + q];
                o1[64 + q] = make_float4(v.x + a3.x, v.y + a3.y, v.z + a3.z, v.w + a3.w);
            }
        }
    }
    __syncthreads();

    // ---- Phase 2: h1 = shifted_softplus(s @ W1 + b1) ----
    const int j = tid & 127;
    const int mbase = (tid >> 7) * 8;   // 0 or 8
    {
        float acc[8] = {0.f, 0.f, 0.f, 0.f, 0.f, 0.f, 0.f, 0.f};
        #pragma unroll 4
        for (int f0 = 0; f0 < 128; f0 += 4) {
            const float w0 = W1[(f0 + 0) * 128 + j];
            const float w1 = W1[(f0 + 1) * 128 + j];
            const float w2 = W1[(f0 + 2) * 128 + j];
            const float w3 = W1[(f0 + 3) * 128 + j];
            #pragma unroll
            for (int m = 0; m < 8; ++m) {
                float4 sv = *(const float4*)&s_lds[mbase + m][f0];
                acc[m] = fmaf(sv.x, w0, acc[m]);
                acc[m] = fmaf(sv.y, w1, acc[m]);
                acc[m] = fmaf(sv.z, w2, acc[m]);
                acc[m] = fmaf(sv.w, w3, acc[m]);
            }
        }
        const float bj = b1[j];
        #pragma unroll
        for (int m = 0; m < 8; ++m) {
            float x = acc[m] + bj;
            // softplus(x) - log(2), numerically stable
            float h = fmaxf(x, 0.f) + log1pf(expf(-fabsf(x))) - LOG2F;
            h_lds[mbase + m][j] = h;
        }
    }
    __syncthreads();

    // ---- Phase 3: out0 = node_sca + h1 @ W2 + b2 ----
    {
        float acc[8] = {0.f, 0.f, 0.f, 0.f, 0.f, 0.f, 0.f, 0.f};
        #pragma unroll 4
        for (int f0 = 0; f0 < 128; f0 += 4) {
            const float w0 = W2[(f0 + 0) * 128 + j];
            const float w1 = W2[(f0 + 1) * 128 + j];
            const float w2 = W2[(f0 + 2) * 128 + j];
            const float w3 = W2[(f0 + 3) * 128 + j];
            #pragma unroll
            for (int m = 0; m < 8; ++m) {
                float4 hv = *(const float4*)&h_lds[mbase + m][f0];
                acc[m] = fmaf(hv.x, w0, acc[m]);
                acc[m] = fmaf(hv.y, w1, acc[m]);
                acc[m] = fmaf(hv.z, w2, acc[m]);
                acc[m] = fmaf(hv.w, w3, acc[m]);
            }
        }
        const float bj = b2[j];
        #pragma unroll
        for (int m = 0; m < 8; ++m) {
            const int n = nbase + mbase + m;
            if (n < N) {
                out0[(long long)n * 128 + j] =
                    node_sca[(long long)n * 128 + j] + acc[m] + bj;
            }
        }
    }
}

extern "C" void kernel_launch(void* const* d_in, const int* in_sizes, int n_in,
                              void* d_out, int out_size, void* d_ws, size_t ws_size,
                              hipStream_t stream) {
    const float* node_sca   = (const float*)d_in[0];
    const float* node_vec   = (const float*)d_in[1];
    const float* edge_feats = (const float*)d_in[2];
    const void*  edge_index = d_in[3];
    const float* W1 = (const float*)d_in[4];
    const float* b1 = (const float*)d_in[5];
    const float* W2 = (const float*)d_in[6];
    const float* b2 = (const float*)d_in[7];

    const int H = in_sizes[5];            // 128
    const int N = in_sizes[0] / H;        // 25000
    const int E = in_sizes[3] / 2;        // 400000 (2*E index elements)
    // K*F = 512, F = 128 (fixed problem shape)

    float* agg = (float*)d_ws;
    const size_t agg_bytes = (size_t)N * 512 * sizeof(float);   // 51.2 MB
    int* flag = (int*)((char*)d_ws + agg_bytes);

    float* out0 = (float*)d_out;               // (N, 128)
    float* out1 = out0 + (long long)N * 128;   // (N, 3, 128)

    hipMemsetAsync(agg, 0, agg_bytes, stream);

    detect_idx_kernel<<<1, 64, 0, stream>>>((const unsigned int*)edge_index, flag);

    {
        const long long total = (long long)E * 128;
        const int block = 256;
        const int grid = (int)((total + block - 1) / block);
        scatter_kernel<<<grid, block, 0, stream>>>(
            (const float4*)edge_feats, edge_index, flag, agg, E);
    }

    {
        const int block = 256;
        const int grid = (N + 15) / 16;
        node_kernel<<<grid, block, 0, stream>>>(
            agg, node_sca, node_vec, W1, b1, W2, b2, out0, out1, N);
    }
}

// Round 2
// 359.765 us; speedup vs baseline: 7.6095x; 7.6095x over previous
//
#include <hip/hip_runtime.h>

#define LOG2F 0.69314718055994530942f

// ---------------------------------------------------------------------------
// Kernel 0: detect whether edge_index is int64 or int32 in memory.
// Node ids < 2^31 so if int64, every odd 32-bit word is 0.
// ---------------------------------------------------------------------------
__global__ void detect_idx_kernel(const unsigned int* __restrict__ words,
                                  int* __restrict__ flag) {
    if (threadIdx.x == 0 && blockIdx.x == 0) {
        int is64 = 1;
        for (int w = 1; w < 400; w += 2) {
            if (words[w] != 0u) { is64 = 0; break; }
        }
        *flag = is64;
    }
}

__device__ __forceinline__ int load_target(const void* idx, const int* flag,
                                           int E, int e) {
    if (*flag) return (int)((const long long*)idx)[E + e];
    return ((const int*)idx)[E + e];
}

// ---------------------------------------------------------------------------
// Kernel 1: histogram of edge targets.
// ---------------------------------------------------------------------------
__global__ __launch_bounds__(256) void hist_kernel(
        const void* __restrict__ idx, const int* __restrict__ flag,
        int* __restrict__ counts, int E) {
    int e = blockIdx.x * blockDim.x + threadIdx.x;
    if (e >= E) return;
    atomicAdd(&counts[load_target(idx, flag, E, e)], 1);
}

// ---------------------------------------------------------------------------
// Kernel 2: single-block exclusive prefix scan of counts -> offsets, cursor.
// ---------------------------------------------------------------------------
__global__ __launch_bounds__(1024) void scan_kernel(
        const int* __restrict__ counts, int* __restrict__ offsets,
        int* __restrict__ cursor, int N) {
    __shared__ int part[1024];
    const int t = threadIdx.x;
    const int L = (N + 1023) / 1024;
    const int lo = t * L;
    const int hi = min(lo + L, N);
    int sum = 0;
    for (int i = lo; i < hi; ++i) sum += counts[i];
    part[t] = sum;
    __syncthreads();
    for (int off = 1; off < 1024; off <<= 1) {
        int v = 0;
        if (t >= off) v = part[t - off];
        __syncthreads();
        if (t >= off) part[t] += v;
        __syncthreads();
    }
    int run = (t == 0) ? 0 : part[t - 1];
    for (int i = lo; i < hi; ++i) {
        offsets[i] = run;
        cursor[i] = run;
        run += counts[i];
    }
}

// ---------------------------------------------------------------------------
// Kernel 3: bucket edge ids by target node.
// ---------------------------------------------------------------------------
__global__ __launch_bounds__(256) void fill_kernel(
        const void* __restrict__ idx, const int* __restrict__ flag,
        int* __restrict__ cursor, int* __restrict__ elist, int E) {
    int e = blockIdx.x * blockDim.x + threadIdx.x;
    if (e >= E) return;
    int n = load_target(idx, flag, E, e);
    int pos = atomicAdd(&cursor[n], 1);
    elist[pos] = e;
}

// ---------------------------------------------------------------------------
// Kernel 4: gather-reduce. One 128-thread block per node.
// Thread q owns float4 column q of the node's (K=4, F=128) accumulator
// (k = q>>5, f4 = q&31). Per edge: 128 threads x 16B = one contiguous 2KB row.
// Writes out1 = node_vec + agg[:,1:,:] and s = sum_k agg (via LDS).
// ---------------------------------------------------------------------------
__global__ __launch_bounds__(128) void gather_kernel(
        const float4* __restrict__ edge_feats4,
        const int* __restrict__ elist,
        const int* __restrict__ offsets,
        const int* __restrict__ counts,
        const float* __restrict__ node_vec,
        float* __restrict__ out1,
        float* __restrict__ s,
        int N) {
    const int n = blockIdx.x;
    const int q = threadIdx.x;            // 0..127
    const int start = offsets[n];
    const int cnt = counts[n];

    float4 acc = make_float4(0.f, 0.f, 0.f, 0.f);
    int e = (cnt > 0) ? elist[start] : 0;
    for (int it = 0; it < cnt; ++it) {
        int enext = (it + 1 < cnt) ? elist[start + it + 1] : 0;
        float4 v = edge_feats4[(long long)e * 128 + q];
        acc.x += v.x; acc.y += v.y; acc.z += v.z; acc.w += v.w;
        e = enext;
    }

    __shared__ float4 lds[128];
    lds[q] = acc;

    // out1 for k >= 1 (no barrier needed: uses own acc)
    if (q >= 32) {
        const int o = (long long)0 + (q - 32);   // 0..95 float4 within row
        float4 v = ((const float4*)node_vec)[(long long)n * 96 + o];
        float4 r = make_float4(v.x + acc.x, v.y + acc.y, v.z + acc.z, v.w + acc.w);
        ((float4*)out1)[(long long)n * 96 + o] = r;
    }
    __syncthreads();
    if (q < 32) {
        float4 a0 = lds[q];
        float4 a1 = lds[32 + q];
        float4 a2 = lds[64 + q];
        float4 a3 = lds[96 + q];
        float4 sv = make_float4(a0.x + a1.x + a2.x + a3.x,
                                a0.y + a1.y + a2.y + a3.y,
                                a0.z + a1.z + a2.z + a3.z,
                                a0.w + a1.w + a2.w + a3.w);
        ((float4*)s)[(long long)n * 32 + q] = sv;
    }
}

// ---------------------------------------------------------------------------
// Kernel 5: per-node MLP. Block = 256 threads, 16 nodes/block.
// ---------------------------------------------------------------------------
__global__ __launch_bounds__(256) void node_kernel(
        const float* __restrict__ s,
        const float* __restrict__ node_sca,
        const float* __restrict__ W1, const float* __restrict__ b1,
        const float* __restrict__ W2, const float* __restrict__ b2,
        float* __restrict__ out0,
        int N) {
    __shared__ float s_lds[16][128];
    __shared__ float h_lds[16][128];

    const int tid = threadIdx.x;
    const int nbase = blockIdx.x * 16;

    // ---- load s tile ----
    {
        const float4* sg = (const float4*)s;
        #pragma unroll
        for (int step = 0; step < 2; ++step) {
            int idx = tid + step * 256;          // 0..511 float4 within tile
            int m = idx >> 5;                    // node within tile
            int q = idx & 31;
            int n = nbase + m;
            float4 v = make_float4(0.f, 0.f, 0.f, 0.f);
            if (n < N) v = sg[(long long)n * 32 + q];
            *(float4*)&s_lds[m][q * 4] = v;
        }
    }
    __syncthreads();

    const int j = tid & 127;
    const int mbase = (tid >> 7) * 8;   // 0 or 8

    // ---- h1 = shifted_softplus(s @ W1 + b1) ----
    {
        float acc[8] = {0.f, 0.f, 0.f, 0.f, 0.f, 0.f, 0.f, 0.f};
        #pragma unroll 4
        for (int f0 = 0; f0 < 128; f0 += 4) {
            const float w0 = W1[(f0 + 0) * 128 + j];
            const float w1 = W1[(f0 + 1) * 128 + j];
            const float w2 = W1[(f0 + 2) * 128 + j];
            const float w3 = W1[(f0 + 3) * 128 + j];
            #pragma unroll
            for (int m = 0; m < 8; ++m) {
                float4 sv = *(const float4*)&s_lds[mbase + m][f0];
                acc[m] = fmaf(sv.x, w0, acc[m]);
                acc[m] = fmaf(sv.y, w1, acc[m]);
                acc[m] = fmaf(sv.z, w2, acc[m]);
                acc[m] = fmaf(sv.w, w3, acc[m]);
            }
        }
        const float bj = b1[j];
        #pragma unroll
        for (int m = 0; m < 8; ++m) {
            float x = acc[m] + bj;
            float h = fmaxf(x, 0.f) + log1pf(expf(-fabsf(x))) - LOG2F;
            h_lds[mbase + m][j] = h;
        }
    }
    __syncthreads();

    // ---- out0 = node_sca + h1 @ W2 + b2 ----
    {
        float acc[8] = {0.f, 0.f, 0.f, 0.f, 0.f, 0.f, 0.f, 0.f};
        #pragma unroll 4
        for (int f0 = 0; f0 < 128; f0 += 4) {
            const float w0 = W2[(f0 + 0) * 128 + j];
            const float w1 = W2[(f0 + 1) * 128 + j];
            const float w2 = W2[(f0 + 2) * 128 + j];
            const float w3 = W2[(f0 + 3) * 128 + j];
            #pragma unroll
            for (int m = 0; m < 8; ++m) {
                float4 hv = *(const float4*)&h_lds[mbase + m][f0];
                acc[m] = fmaf(hv.x, w0, acc[m]);
                acc[m] = fmaf(hv.y, w1, acc[m]);
                acc[m] = fmaf(hv.z, w2, acc[m]);
                acc[m] = fmaf(hv.w, w3, acc[m]);
            }
        }
        const float bj = b2[j];
        #pragma unroll
        for (int m = 0; m < 8; ++m) {
            const int n = nbase + mbase + m;
            if (n < N) {
                out0[(long long)n * 128 + j] =
                    node_sca[(long long)n * 128 + j] + acc[m] + bj;
            }
        }
    }
}

extern "C" void kernel_launch(void* const* d_in, const int* in_sizes, int n_in,
                              void* d_out, int out_size, void* d_ws, size_t ws_size,
                              hipStream_t stream) {
    const float* node_sca   = (const float*)d_in[0];
    const float* node_vec   = (const float*)d_in[1];
    const float* edge_feats = (const float*)d_in[2];
    const void*  edge_index = d_in[3];
    const float* W1 = (const float*)d_in[4];
    const float* b1 = (const float*)d_in[5];
    const float* W2 = (const float*)d_in[6];
    const float* b2 = (const float*)d_in[7];

    const int H = in_sizes[5];            // 128
    const int N = in_sizes[0] / H;        // 25000
    const int E = in_sizes[3] / 2;        // 400000

    // workspace layout
    char* w = (char*)d_ws;
    int* counts  = (int*)w;  w += sizeof(int) * (size_t)N;
    int* offsets = (int*)w;  w += sizeof(int) * (size_t)N;
    int* cursor  = (int*)w;  w += sizeof(int) * (size_t)N;
    int* elist   = (int*)w;  w += sizeof(int) * (size_t)E;
    size_t off = (size_t)(w - (char*)d_ws);
    off = (off + 15) & ~(size_t)15;
    float* s = (float*)((char*)d_ws + off);
    int* flag = (int*)((char*)d_ws + off + (size_t)N * 128 * sizeof(float));

    float* out0 = (float*)d_out;               // (N, 128)
    float* out1 = out0 + (long long)N * 128;   // (N, 3, 128)

    hipMemsetAsync(counts, 0, sizeof(int) * (size_t)N, stream);

    detect_idx_kernel<<<1, 64, 0, stream>>>((const unsigned int*)edge_index, flag);

    hist_kernel<<<(E + 255) / 256, 256, 0, stream>>>(edge_index, flag, counts, E);

    scan_kernel<<<1, 1024, 0, stream>>>(counts, offsets, cursor, N);

    fill_kernel<<<(E + 255) / 256, 256, 0, stream>>>(edge_index, flag, cursor, elist, E);

    gather_kernel<<<N, 128, 0, stream>>>(
        (const float4*)edge_feats, elist, offsets, counts, node_vec, out1, s, N);

    node_kernel<<<(N + 15) / 16, 256, 0, stream>>>(
        s, node_sca, W1, b1, W2, b2, out0, N);
}

// Round 3
// 357.729 us; speedup vs baseline: 7.6528x; 1.0057x over previous
//
#include <hip/hip_runtime.h>

#define LOG2F 0.69314718055994530942f

// ---------------------------------------------------------------------------
// Kernel 0: detect whether edge_index is int64 or int32 in memory.
// Node ids < 2^31 so if int64, every odd 32-bit word is 0.
// Wave-parallel: 64 lanes probe ~4 words each, ballot-reduce.
// ---------------------------------------------------------------------------
__global__ void detect_idx_kernel(const unsigned int* __restrict__ words,
                                  int* __restrict__ flag) {
    const int lane = threadIdx.x;          // 0..63
    unsigned int acc = 0;
    // probe odd words 1,3,...,511 (256 probes, 4 per lane)
    #pragma unroll
    for (int r = 0; r < 4; ++r) {
        acc |= words[1 + 2 * (lane + 64 * r)];
    }
    int any_nonzero = __any(acc != 0u);
    if (lane == 0) *flag = any_nonzero ? 0 : 1;
}

__device__ __forceinline__ int load_target(const void* idx, const int* flag,
                                           int E, int e) {
    if (*flag) return (int)((const long long*)idx)[E + e];
    return ((const int*)idx)[E + e];
}

// ---------------------------------------------------------------------------
// Kernel 1: histogram of edge targets.
// ---------------------------------------------------------------------------
__global__ __launch_bounds__(256) void hist_kernel(
        const void* __restrict__ idx, const int* __restrict__ flag,
        int* __restrict__ counts, int E) {
    int e = blockIdx.x * blockDim.x + threadIdx.x;
    if (e >= E) return;
    atomicAdd(&counts[load_target(idx, flag, E, e)], 1);
}

// ---------------------------------------------------------------------------
// Kernel 2: single-block exclusive prefix scan of counts -> offsets, cursor.
// ---------------------------------------------------------------------------
__global__ __launch_bounds__(1024) void scan_kernel(
        const int* __restrict__ counts, int* __restrict__ offsets,
        int* __restrict__ cursor, int N) {
    __shared__ int part[1024];
    const int t = threadIdx.x;
    const int L = (N + 1023) / 1024;
    const int lo = t * L;
    const int hi = min(lo + L, N);
    int sum = 0;
    for (int i = lo; i < hi; ++i) sum += counts[i];
    part[t] = sum;
    __syncthreads();
    for (int off = 1; off < 1024; off <<= 1) {
        int v = 0;
        if (t >= off) v = part[t - off];
        __syncthreads();
        if (t >= off) part[t] += v;
        __syncthreads();
    }
    int run = (t == 0) ? 0 : part[t - 1];
    for (int i = lo; i < hi; ++i) {
        offsets[i] = run;
        cursor[i] = run;
        run += counts[i];
    }
}

// ---------------------------------------------------------------------------
// Kernel 3: bucket edge ids by target node.
// ---------------------------------------------------------------------------
__global__ __launch_bounds__(256) void fill_kernel(
        const void* __restrict__ idx, const int* __restrict__ flag,
        int* __restrict__ cursor, int* __restrict__ elist, int E) {
    int e = blockIdx.x * blockDim.x + threadIdx.x;
    if (e >= E) return;
    int n = load_target(idx, flag, E, e);
    int pos = atomicAdd(&cursor[n], 1);
    elist[pos] = e;
}

// ---------------------------------------------------------------------------
// Kernel 4: gather-reduce. One 128-thread block per node.
// Edge ids staged in LDS (one coalesced pass), then row loop unrolled x4 so
// 4 x 2KB row loads are in flight per block (no global address chain).
// Writes out1 = node_vec + agg[:,1:,:] and s = sum_k agg.
// ---------------------------------------------------------------------------
__global__ __launch_bounds__(128) void gather_kernel(
        const float4* __restrict__ edge_feats4,
        const int* __restrict__ elist,
        const int* __restrict__ offsets,
        const int* __restrict__ counts,
        const float* __restrict__ node_vec,
        float* __restrict__ out1,
        float* __restrict__ s,
        int N) {
    const int n = blockIdx.x;
    const int q = threadIdx.x;            // 0..127
    const int start = offsets[n];
    const int cnt = counts[n];

    __shared__ int el[256];
    __shared__ float4 lds[128];

    float4 acc = make_float4(0.f, 0.f, 0.f, 0.f);

    for (int base = 0; base < cnt; base += 256) {
        const int chunk = min(cnt - base, 256);
        if (q < chunk) el[q] = elist[start + base + q];
        if (q + 128 < chunk) el[q + 128] = elist[start + base + q + 128];
        __syncthreads();

        int it = 0;
        for (; it + 4 <= chunk; it += 4) {
            const long long e0 = el[it + 0];
            const long long e1 = el[it + 1];
            const long long e2 = el[it + 2];
            const long long e3 = el[it + 3];
            float4 v0 = edge_feats4[e0 * 128 + q];
            float4 v1 = edge_feats4[e1 * 128 + q];
            float4 v2 = edge_feats4[e2 * 128 + q];
            float4 v3 = edge_feats4[e3 * 128 + q];
            acc.x += (v0.x + v1.x) + (v2.x + v3.x);
            acc.y += (v0.y + v1.y) + (v2.y + v3.y);
            acc.z += (v0.z + v1.z) + (v2.z + v3.z);
            acc.w += (v0.w + v1.w) + (v2.w + v3.w);
        }
        for (; it < chunk; ++it) {
            const long long e = el[it];
            float4 v = edge_feats4[e * 128 + q];
            acc.x += v.x; acc.y += v.y; acc.z += v.z; acc.w += v.w;
        }
        __syncthreads();   // protect el before next chunk overwrite
    }

    lds[q] = acc;

    // out1 for k >= 1 (uses own acc, no barrier needed)
    if (q >= 32) {
        const int o = q - 32;   // 0..95 float4 within (3,128) row
        float4 v = ((const float4*)node_vec)[(long long)n * 96 + o];
        ((float4*)out1)[(long long)n * 96 + o] =
            make_float4(v.x + acc.x, v.y + acc.y, v.z + acc.z, v.w + acc.w);
    }
    __syncthreads();
    if (q < 32) {
        float4 a0 = lds[q];
        float4 a1 = lds[32 + q];
        float4 a2 = lds[64 + q];
        float4 a3 = lds[96 + q];
        ((float4*)s)[(long long)n * 32 + q] =
            make_float4(a0.x + a1.x + a2.x + a3.x,
                        a0.y + a1.y + a2.y + a3.y,
                        a0.z + a1.z + a2.z + a3.z,
                        a0.w + a1.w + a2.w + a3.w);
    }
}

// ---------------------------------------------------------------------------
// Kernel 5: per-node MLP. Block = 256 threads, 16 nodes/block.
// ---------------------------------------------------------------------------
__global__ __launch_bounds__(256) void node_kernel(
        const float* __restrict__ s,
        const float* __restrict__ node_sca,
        const float* __restrict__ W1, const float* __restrict__ b1,
        const float* __restrict__ W2, const float* __restrict__ b2,
        float* __restrict__ out0,
        int N) {
    __shared__ float s_lds[16][128];
    __shared__ float h_lds[16][128];

    const int tid = threadIdx.x;
    const int nbase = blockIdx.x * 16;

    {
        const float4* sg = (const float4*)s;
        #pragma unroll
        for (int step = 0; step < 2; ++step) {
            int idx = tid + step * 256;
            int m = idx >> 5;
            int q = idx & 31;
            int n = nbase + m;
            float4 v = make_float4(0.f, 0.f, 0.f, 0.f);
            if (n < N) v = sg[(long long)n * 32 + q];
            *(float4*)&s_lds[m][q * 4] = v;
        }
    }
    __syncthreads();

    const int j = tid & 127;
    const int mbase = (tid >> 7) * 8;

    {
        float acc[8] = {0.f, 0.f, 0.f, 0.f, 0.f, 0.f, 0.f, 0.f};
        #pragma unroll 4
        for (int f0 = 0; f0 < 128; f0 += 4) {
            const float w0 = W1[(f0 + 0) * 128 + j];
            const float w1 = W1[(f0 + 1) * 128 + j];
            const float w2 = W1[(f0 + 2) * 128 + j];
            const float w3 = W1[(f0 + 3) * 128 + j];
            #pragma unroll
            for (int m = 0; m < 8; ++m) {
                float4 sv = *(const float4*)&s_lds[mbase + m][f0];
                acc[m] = fmaf(sv.x, w0, acc[m]);
                acc[m] = fmaf(sv.y, w1, acc[m]);
                acc[m] = fmaf(sv.z, w2, acc[m]);
                acc[m] = fmaf(sv.w, w3, acc[m]);
            }
        }
        const float bj = b1[j];
        #pragma unroll
        for (int m = 0; m < 8; ++m) {
            float x = acc[m] + bj;
            float h = fmaxf(x, 0.f) + log1pf(expf(-fabsf(x))) - LOG2F;
            h_lds[mbase + m][j] = h;
        }
    }
    __syncthreads();

    {
        float acc[8] = {0.f, 0.f, 0.f, 0.f, 0.f, 0.f, 0.f, 0.f};
        #pragma unroll 4
        for (int f0 = 0; f0 < 128; f0 += 4) {
            const float w0 = W2[(f0 + 0) * 128 + j];
            const float w1 = W2[(f0 + 1) * 128 + j];
            const float w2 = W2[(f0 + 2) * 128 + j];
            const float w3 = W2[(f0 + 3) * 128 + j];
            #pragma unroll
            for (int m = 0; m < 8; ++m) {
                float4 hv = *(const float4*)&h_lds[mbase + m][f0];
                acc[m] = fmaf(hv.x, w0, acc[m]);
                acc[m] = fmaf(hv.y, w1, acc[m]);
                acc[m] = fmaf(hv.z, w2, acc[m]);
                acc[m] = fmaf(hv.w, w3, acc[m]);
            }
        }
        const float bj = b2[j];
        #pragma unroll
        for (int m = 0; m < 8; ++m) {
            const int n = nbase + mbase + m;
            if (n < N) {
                out0[(long long)n * 128 + j] =
                    node_sca[(long long)n * 128 + j] + acc[m] + bj;
            }
        }
    }
}

extern "C" void kernel_launch(void* const* d_in, const int* in_sizes, int n_in,
                              void* d_out, int out_size, void* d_ws, size_t ws_size,
                              hipStream_t stream) {
    const float* node_sca   = (const float*)d_in[0];
    const float* node_vec   = (const float*)d_in[1];
    const float* edge_feats = (const float*)d_in[2];
    const void*  edge_index = d_in[3];
    const float* W1 = (const float*)d_in[4];
    const float* b1 = (const float*)d_in[5];
    const float* W2 = (const float*)d_in[6];
    const float* b2 = (const float*)d_in[7];

    const int H = in_sizes[5];            // 128
    const int N = in_sizes[0] / H;        // 25000
    const int E = in_sizes[3] / 2;        // 400000

    char* w = (char*)d_ws;
    int* counts  = (int*)w;  w += sizeof(int) * (size_t)N;
    int* offsets = (int*)w;  w += sizeof(int) * (size_t)N;
    int* cursor  = (int*)w;  w += sizeof(int) * (size_t)N;
    int* elist   = (int*)w;  w += sizeof(int) * (size_t)E;
    size_t off = (size_t)(w - (char*)d_ws);
    off = (off + 15) & ~(size_t)15;
    float* s = (float*)((char*)d_ws + off);
    int* flag = (int*)((char*)d_ws + off + (size_t)N * 128 * sizeof(float));

    float* out0 = (float*)d_out;               // (N, 128)
    float* out1 = out0 + (long long)N * 128;   // (N, 3, 128)

    hipMemsetAsync(counts, 0, sizeof(int) * (size_t)N, stream);

    detect_idx_kernel<<<1, 64, 0, stream>>>((const unsigned int*)edge_index, flag);

    hist_kernel<<<(E + 255) / 256, 256, 0, stream>>>(edge_index, flag, counts, E);

    scan_kernel<<<1, 1024, 0, stream>>>(counts, offsets, cursor, N);

    fill_kernel<<<(E + 255) / 256, 256, 0, stream>>>(edge_index, flag, cursor, elist, E);

    gather_kernel<<<N, 128, 0, stream>>>(
        (const float4*)edge_feats, elist, offsets, counts, node_vec, out1, s, N);

    node_kernel<<<(N + 15) / 16, 256, 0, stream>>>(
        s, node_sca, W1, b1, W2, b2, out0, N);
}

// Round 4
// 286.387 us; speedup vs baseline: 9.5592x; 1.2491x over previous
//
#include <hip/hip_runtime.h>

#define LOG2F 0.69314718055994530942f
#define CAP 64   // per-node bucket capacity; Poisson(16) max ~45, overflow path below

// ---------------------------------------------------------------------------
// Kernel 0: zero counts/ovf_cnt + detect int64 vs int32 edge_index layout.
// Block 0 lanes 0..63 probe 256 odd 32-bit words (all-zero <=> int64).
// ---------------------------------------------------------------------------
__global__ __launch_bounds__(256) void zero_detect_kernel(
        const unsigned int* __restrict__ words,
        int* __restrict__ counts, int* __restrict__ ovf_cnt,
        int* __restrict__ flag, int N) {
    const int gid = blockIdx.x * blockDim.x + threadIdx.x;
    if (gid < N) counts[gid] = 0;
    if (gid == 0) *ovf_cnt = 0;
    if (blockIdx.x == 0 && threadIdx.x < 64) {
        const int lane = threadIdx.x;
        unsigned int acc = 0;
        #pragma unroll
        for (int r = 0; r < 4; ++r) acc |= words[1 + 2 * (lane + 64 * r)];
        int any_nonzero = __any(acc != 0u);
        if (lane == 0) *flag = any_nonzero ? 0 : 1;
    }
}

__device__ __forceinline__ int load_target(const void* idx, const int* flag,
                                           int E, int e) {
    if (*flag) return (int)((const long long*)idx)[E + e];
    return ((const int*)idx)[E + e];
}

// ---------------------------------------------------------------------------
// Kernel 1: direct bucketing (fused hist+fill, no scan).
// ---------------------------------------------------------------------------
__global__ __launch_bounds__(256) void bucket_kernel(
        const void* __restrict__ idx, const int* __restrict__ flag,
        int* __restrict__ counts, int* __restrict__ elist64,
        int* __restrict__ ovf_cnt, int* __restrict__ ovf_n,
        int* __restrict__ ovf_e, int E) {
    int e = blockIdx.x * blockDim.x + threadIdx.x;
    if (e >= E) return;
    int n = load_target(idx, flag, E, e);
    int pos = atomicAdd(&counts[n], 1);
    if (pos < CAP) {
        elist64[(n << 6) + pos] = e;
    } else {
        int op = atomicAdd(ovf_cnt, 1);
        ovf_n[op] = n;
        ovf_e[op] = e;
    }
}

// ---------------------------------------------------------------------------
// Kernel 2: gather-reduce. One 256-thread block per node; two sub-halves each
// own half the edges (unroll x4) -> 8 independent 2KB row streams in flight.
// Writes out1 = node_vec + agg[:,1:,:] and s = sum_k agg.
// ---------------------------------------------------------------------------
__global__ __launch_bounds__(256) void gather_kernel(
        const float4* __restrict__ edge_feats4,
        const int* __restrict__ elist64,
        const int* __restrict__ counts,
        const int* __restrict__ ovf_cnt,
        const int* __restrict__ ovf_n,
        const int* __restrict__ ovf_e,
        const float* __restrict__ node_vec,
        float* __restrict__ out1,
        float* __restrict__ s,
        int N) {
    const int n = blockIdx.x;
    const int tid = threadIdx.x;
    const int sub = tid >> 7;          // 0 or 1
    const int q = tid & 127;           // float4 column within (K=4,F=128) row

    const int cnt = counts[n];
    const int cin = min(cnt, CAP);

    __shared__ int el[CAP];
    __shared__ float4 lds[256];

    if (tid < cin) el[tid] = elist64[(n << 6) + tid];
    __syncthreads();

    const int h0 = cin >> 1;
    const int mybase = sub ? h0 : 0;
    const int myc = sub ? (cin - h0) : h0;

    float4 acc = make_float4(0.f, 0.f, 0.f, 0.f);
    int it = 0;
    for (; it + 4 <= myc; it += 4) {
        const long long e0 = el[mybase + it + 0];
        const long long e1 = el[mybase + it + 1];
        const long long e2 = el[mybase + it + 2];
        const long long e3 = el[mybase + it + 3];
        float4 v0 = edge_feats4[e0 * 128 + q];
        float4 v1 = edge_feats4[e1 * 128 + q];
        float4 v2 = edge_feats4[e2 * 128 + q];
        float4 v3 = edge_feats4[e3 * 128 + q];
        acc.x += (v0.x + v1.x) + (v2.x + v3.x);
        acc.y += (v0.y + v1.y) + (v2.y + v3.y);
        acc.z += (v0.z + v1.z) + (v2.z + v3.z);
        acc.w += (v0.w + v1.w) + (v2.w + v3.w);
    }
    for (; it < myc; ++it) {
        const long long e = el[mybase + it];
        float4 v = edge_feats4[e * 128 + q];
        acc.x += v.x; acc.y += v.y; acc.z += v.z; acc.w += v.w;
    }

    lds[tid] = acc;
    __syncthreads();

    if (tid < 128) {
        float4 a = lds[q];
        float4 b = lds[128 + q];
        a.x += b.x; a.y += b.y; a.z += b.z; a.w += b.w;
        if (cnt > CAP) {              // rare overflow path (correctness only)
            int oc = *ovf_cnt;
            for (int i = 0; i < oc; ++i) {
                if (ovf_n[i] == n) {
                    float4 v = edge_feats4[(long long)ovf_e[i] * 128 + q];
                    a.x += v.x; a.y += v.y; a.z += v.z; a.w += v.w;
                }
            }
        }
        lds[q] = a;
    }
    __syncthreads();

    if (tid >= 32 && tid < 128) {     // out1 for k>=1: 96 float4 per node
        const int o = tid - 32;
        float4 a = lds[tid];
        float4 v = ((const float4*)node_vec)[(long long)n * 96 + o];
        ((float4*)out1)[(long long)n * 96 + o] =
            make_float4(v.x + a.x, v.y + a.y, v.z + a.z, v.w + a.w);
    }
    if (tid < 32) {                   // s = sum over k
        float4 a0 = lds[tid];
        float4 a1 = lds[32 + tid];
        float4 a2 = lds[64 + tid];
        float4 a3 = lds[96 + tid];
        ((float4*)s)[(long long)n * 32 + tid] =
            make_float4(a0.x + a1.x + a2.x + a3.x,
                        a0.y + a1.y + a2.y + a3.y,
                        a0.z + a1.z + a2.z + a3.z,
                        a0.w + a1.w + a2.w + a3.w);
    }
}

// ---------------------------------------------------------------------------
// Kernel 3: per-node MLP. Block = 256 threads, 16 nodes/block.
// ---------------------------------------------------------------------------
__global__ __launch_bounds__(256) void node_kernel(
        const float* __restrict__ s,
        const float* __restrict__ node_sca,
        const float* __restrict__ W1, const float* __restrict__ b1,
        const float* __restrict__ W2, const float* __restrict__ b2,
        float* __restrict__ out0,
        int N) {
    __shared__ float s_lds[16][128];
    __shared__ float h_lds[16][128];

    const int tid = threadIdx.x;
    const int nbase = blockIdx.x * 16;

    {
        const float4* sg = (const float4*)s;
        #pragma unroll
        for (int step = 0; step < 2; ++step) {
            int idx = tid + step * 256;
            int m = idx >> 5;
            int q = idx & 31;
            int n = nbase + m;
            float4 v = make_float4(0.f, 0.f, 0.f, 0.f);
            if (n < N) v = sg[(long long)n * 32 + q];
            *(float4*)&s_lds[m][q * 4] = v;
        }
    }
    __syncthreads();

    const int j = tid & 127;
    const int mbase = (tid >> 7) * 8;

    {
        float acc[8] = {0.f, 0.f, 0.f, 0.f, 0.f, 0.f, 0.f, 0.f};
        #pragma unroll 4
        for (int f0 = 0; f0 < 128; f0 += 4) {
            const float w0 = W1[(f0 + 0) * 128 + j];
            const float w1 = W1[(f0 + 1) * 128 + j];
            const float w2 = W1[(f0 + 2) * 128 + j];
            const float w3 = W1[(f0 + 3) * 128 + j];
            #pragma unroll
            for (int m = 0; m < 8; ++m) {
                float4 sv = *(const float4*)&s_lds[mbase + m][f0];
                acc[m] = fmaf(sv.x, w0, acc[m]);
                acc[m] = fmaf(sv.y, w1, acc[m]);
                acc[m] = fmaf(sv.z, w2, acc[m]);
                acc[m] = fmaf(sv.w, w3, acc[m]);
            }
        }
        const float bj = b1[j];
        #pragma unroll
        for (int m = 0; m < 8; ++m) {
            float x = acc[m] + bj;
            float h = fmaxf(x, 0.f) + log1pf(expf(-fabsf(x))) - LOG2F;
            h_lds[mbase + m][j] = h;
        }
    }
    __syncthreads();

    {
        float acc[8] = {0.f, 0.f, 0.f, 0.f, 0.f, 0.f, 0.f, 0.f};
        #pragma unroll 4
        for (int f0 = 0; f0 < 128; f0 += 4) {
            const float w0 = W2[(f0 + 0) * 128 + j];
            const float w1 = W2[(f0 + 1) * 128 + j];
            const float w2 = W2[(f0 + 2) * 128 + j];
            const float w3 = W2[(f0 + 3) * 128 + j];
            #pragma unroll
            for (int m = 0; m < 8; ++m) {
                float4 hv = *(const float4*)&h_lds[mbase + m][f0];
                acc[m] = fmaf(hv.x, w0, acc[m]);
                acc[m] = fmaf(hv.y, w1, acc[m]);
                acc[m] = fmaf(hv.z, w2, acc[m]);
                acc[m] = fmaf(hv.w, w3, acc[m]);
            }
        }
        const float bj = b2[j];
        #pragma unroll
        for (int m = 0; m < 8; ++m) {
            const int n = nbase + mbase + m;
            if (n < N) {
                out0[(long long)n * 128 + j] =
                    node_sca[(long long)n * 128 + j] + acc[m] + bj;
            }
        }
    }
}

extern "C" void kernel_launch(void* const* d_in, const int* in_sizes, int n_in,
                              void* d_out, int out_size, void* d_ws, size_t ws_size,
                              hipStream_t stream) {
    const float* node_sca   = (const float*)d_in[0];
    const float* node_vec   = (const float*)d_in[1];
    const float* edge_feats = (const float*)d_in[2];
    const void*  edge_index = d_in[3];
    const float* W1 = (const float*)d_in[4];
    const float* b1 = (const float*)d_in[5];
    const float* W2 = (const float*)d_in[6];
    const float* b2 = (const float*)d_in[7];

    const int H = in_sizes[5];            // 128
    const int N = in_sizes[0] / H;        // 25000
    const int E = in_sizes[3] / 2;        // 400000

    // workspace layout (16B-aligned chunks)
    char* w = (char*)d_ws;
    auto take = [&](size_t bytes) {
        char* p = w;
        w += (bytes + 15) & ~(size_t)15;
        return p;
    };
    int*   counts  = (int*)take(sizeof(int) * (size_t)N);
    int*   elist64 = (int*)take(sizeof(int) * (size_t)N * CAP);
    int*   ovf_cnt = (int*)take(sizeof(int));
    int*   ovf_n   = (int*)take(sizeof(int) * (size_t)E);
    int*   ovf_e   = (int*)take(sizeof(int) * (size_t)E);
    float* s       = (float*)take(sizeof(float) * (size_t)N * 128);
    int*   flag    = (int*)take(sizeof(int));

    float* out0 = (float*)d_out;               // (N, 128)
    float* out1 = out0 + (long long)N * 128;   // (N, 3, 128)

    zero_detect_kernel<<<(N + 255) / 256, 256, 0, stream>>>(
        (const unsigned int*)edge_index, counts, ovf_cnt, flag, N);

    bucket_kernel<<<(E + 255) / 256, 256, 0, stream>>>(
        edge_index, flag, counts, elist64, ovf_cnt, ovf_n, ovf_e, E);

    gather_kernel<<<N, 256, 0, stream>>>(
        (const float4*)edge_feats, elist64, counts, ovf_cnt, ovf_n, ovf_e,
        node_vec, out1, s, N);

    node_kernel<<<(N + 15) / 16, 256, 0, stream>>>(
        s, node_sca, W1, b1, W2, b2, out0, N);
}